// Round 18
// baseline (115.986 us; speedup 1.0000x reference)
//
#include <hip/hip_runtime.h>

// LIF neuron forward, v12: two interleaved chains per lane (ILP over the
// 7-cyc dependent-VALU latency) + vcc-gap scheduling.
// V = leak*V + I; spike = (V >= 1); V -= spike.
// current: [B=8, S=4096, D=1024] f32, membrane: [B, D] f32.
// Outputs concatenated: spikes [B,S,D] then mem_final [B,D], all f32.
//
// v11 evidence: cadence 43cy/step == ~6 strictly-ordered ops x ~7cy
// dependent-issue latency at 1-wave occupancy (no TLP on the consumer
// SIMD). v12: 2 independent channel-chains per lane interleaved in ONE
// asm block -> B fills A's latency gaps (r7 proved 2ch/lane = 1.7x per
// channel; its loss was grid shrink, not repeated here). w=v-1 moved into
// the cmp->cndmask vcc-forwarding gap. Consumer lanes 0-15 own channel
// pairs (2L,2L+1) via ds_read_b64 (conflict-free; lanes 16+ duplicate
// lane&15 harmlessly = broadcast). Masks: v_cmp -> SGPR pair, writelane
// banks step s into lane s of vmlA/vmlB; one ds_write_b64 per 32 steps.
// Skeleton = v11: 256 blocks, CPB=32, CHUNK=256, NH=16, raw barriers,
// producer distance-1 vmcnt(0), writers expand masks -> float4 stores.
//
// Numerics: identical arithmetic to r5-r17 (absmax 7.6e-6): v=0.9*mem+c
// (mul-then-add, 0x3f666666=0.9f), f=(v>=1.0), mem=f?v-1:v. Bit-exact.

#define LIF_B 8
#define LIF_S 4096
#define LIF_D 1024
#define CHUNK 256
#define NH    (LIF_S / CHUNK)   // 16
#define CPB   32                // channels per block

typedef __attribute__((address_space(3))) unsigned int lds_uint;
typedef const __attribute__((address_space(1))) unsigned int glb_uint;

// stage one 32KB chunk (256 rows x 32 ch) with 32 x 1KB global_load_lds.
__device__ __forceinline__ void stage_chunk32(const float* gwin, int tb,
                                              int prow, int pcol,
                                              float* slotbase) {
    #pragma unroll
    for (int f = 0; f < CHUNK / 8; ++f) {
        const float* src = gwin + (size_t)(tb + 8 * f + prow) * LIF_D + pcol;
        __builtin_amdgcn_global_load_lds(
            (glb_uint*)(const void*)src,
            (lds_uint*)(void*)(slotbase + (size_t)f * 256), 16, 0, 0);
    }
}

// One global time step for TWO independent channel chains, interleaved.
// Chain: mul -> add -> cmp -> (w fills vcc gap) -> cndmask. B fills A's
// dependency stalls. Spike masks land in SGPR pairs; banked via writelane.
template<int LB>
__device__ __forceinline__ void lif_step2(float cA, float cB,
                                          float& memA, float& memB,
                                          unsigned& vmlA, unsigned& vmlB) {
    float vA, vB, wA, wB;
    unsigned long long mA, mB;
    asm volatile(
        "v_mul_f32 %2, 0x3f666666, %6\n\t"   // vA = 0.9*memA
        "v_mul_f32 %3, 0x3f666666, %7\n\t"   // vB = 0.9*memB
        "v_add_f32 %2, %2, %8\n\t"           // vA += cA
        "v_add_f32 %3, %3, %9\n\t"           // vB += cB
        "v_cmp_ge_f32 %0, %2, 1.0\n\t"       // maskA -> sgpr pair
        "v_add_f32 %4, -1.0, %2\n\t"         // wA = vA-1 (fills vcc gap)
        "v_cmp_ge_f32 %1, %3, 1.0\n\t"       // maskB
        "v_add_f32 %5, -1.0, %3\n\t"         // wB
        "v_cndmask_b32 %6, %2, %4, %0\n\t"   // memA = fA ? wA : vA
        "v_cndmask_b32 %7, %3, %5, %1"       // memB = fB ? wB : vB
        : "=&s"(mA), "=&s"(mB), "=&v"(vA), "=&v"(vB), "=&v"(wA), "=&v"(wB),
          "+v"(memA), "+v"(memB)
        : "v"(cA), "v"(cB));
    asm volatile("v_writelane_b32 %0, %1, %2"
                 : "+v"(vmlA) : "s"((unsigned)mA), "n"(LB));
    asm volatile("v_writelane_b32 %0, %1, %2"
                 : "+v"(vmlB) : "s"((unsigned)mB), "n"(LB));
}

#define STEPS16(P, B0) do { \
    lif_step2<(B0)+ 0>(P[ 0].x, P[ 0].y, memA, memB, vmlA, vmlB); \
    lif_step2<(B0)+ 1>(P[ 1].x, P[ 1].y, memA, memB, vmlA, vmlB); \
    lif_step2<(B0)+ 2>(P[ 2].x, P[ 2].y, memA, memB, vmlA, vmlB); \
    lif_step2<(B0)+ 3>(P[ 3].x, P[ 3].y, memA, memB, vmlA, vmlB); \
    lif_step2<(B0)+ 4>(P[ 4].x, P[ 4].y, memA, memB, vmlA, vmlB); \
    lif_step2<(B0)+ 5>(P[ 5].x, P[ 5].y, memA, memB, vmlA, vmlB); \
    lif_step2<(B0)+ 6>(P[ 6].x, P[ 6].y, memA, memB, vmlA, vmlB); \
    lif_step2<(B0)+ 7>(P[ 7].x, P[ 7].y, memA, memB, vmlA, vmlB); \
    lif_step2<(B0)+ 8>(P[ 8].x, P[ 8].y, memA, memB, vmlA, vmlB); \
    lif_step2<(B0)+ 9>(P[ 9].x, P[ 9].y, memA, memB, vmlA, vmlB); \
    lif_step2<(B0)+10>(P[10].x, P[10].y, memA, memB, vmlA, vmlB); \
    lif_step2<(B0)+11>(P[11].x, P[11].y, memA, memB, vmlA, vmlB); \
    lif_step2<(B0)+12>(P[12].x, P[12].y, memA, memB, vmlA, vmlB); \
    lif_step2<(B0)+13>(P[13].x, P[13].y, memA, memB, vmlA, vmlB); \
    lif_step2<(B0)+14>(P[14].x, P[14].y, memA, memB, vmlA, vmlB); \
    lif_step2<(B0)+15>(P[15].x, P[15].y, memA, memB, vmlA, vmlB); \
} while (0)

__global__ __launch_bounds__(256, 1) void lif_v12_kernel(
    const float* __restrict__ current,
    const float* __restrict__ membrane,
    float* __restrict__ spikes,
    float* __restrict__ mem_out)
{
    #pragma clang fp contract(off)

    __shared__ __align__(16) float in_ring[2][CHUNK][CPB];   // 64 KB
    __shared__ uint2 mask2[2][8][64];                        // 8 KB step masks

    const int wid  = threadIdx.x >> 6;   // 0=consumer 1=producer 2,3=writers
    const int lane = threadIdx.x & 63;
    const int blk  = blockIdx.x;         // 0..255
    const int bb   = blk >> 5;           // batch (1024/32 = 32 ch-blocks)
    const int ch0  = (blk & 31) * CPB;

    const float* gwin  = current + (size_t)bb * LIF_S * LIF_D + ch0;
    float*       sbase = spikes  + (size_t)bb * LIF_S * LIF_D + ch0;

    const int prow = lane >> 3;          // producer 8-row mapping
    const int pcol = (lane & 7) * 4;
    const int lx   = lane & 15;          // consumer channel-pair index

    float memA = 0.0f, memB = 0.0f;

    // ---- prologue: producer stages chunk 0; consumer loads membrane ----
    if (wid == 1) {
        stage_chunk32(gwin, 0, prow, pcol, &in_ring[0][0][0]);
        asm volatile("s_waitcnt vmcnt(0)" ::: "memory");
    } else if (wid == 0) {
        const float2 mm = *(const float2*)&membrane[bb * LIF_D + ch0 + 2 * lx];
        memA = mm.x; memB = mm.y;
    }
    __builtin_amdgcn_s_barrier();
    asm volatile("" ::: "memory");

    for (int h = 0; h < NH; ++h) {
        if (wid == 0) {
            // ---- consumer: 256 steps, 2 chains/lane, 8 mask groups ----
            const float2* ib2 = (const float2*)&in_ring[h & 1][0][0];
            float2 PA[16], PB[16];
            #pragma unroll
            for (int j = 0; j < 16; ++j) PA[j] = ib2[j * 16 + lx];
            #pragma unroll
            for (int j = 0; j < 16; ++j) PB[j] = ib2[(16 + j) * 16 + lx];
            unsigned vmlA = 0, vmlB = 0;

            for (int g = 0; g < 8; ++g) {
                STEPS16(PA, 0);                       // steps 32g+0..15
                if (g < 7) {
                    #pragma unroll
                    for (int j = 0; j < 16; ++j)
                        PA[j] = ib2[((2 * g + 2) * 16 + j) * 16 + lx];
                }
                STEPS16(PB, 16);                      // steps 32g+16..31
                mask2[h & 1][g][lane] = make_uint2(vmlA, vmlB);
                if (g < 7) {
                    #pragma unroll
                    for (int j = 0; j < 16; ++j)
                        PB[j] = ib2[((2 * g + 3) * 16 + j) * 16 + lx];
                }
            }
            asm volatile("s_waitcnt lgkmcnt(0)" ::: "memory");
        } else if (wid == 1) {
            // ---- producer: stage chunk h+1 into the other slot ----
            if (h + 1 < NH) {
                stage_chunk32(gwin, (h + 1) * CHUNK, prow, pcol,
                              &in_ring[(h + 1) & 1][0][0]);
                asm volatile("s_waitcnt vmcnt(0)" ::: "memory");
            }
        } else {
            // ---- writers: expand masks of phase h-1 -> float4 stores ----
            if (h >= 1) {
                const int ph = (h - 1) & 1;
                const int tb = (h - 1) * CHUNK;
                const int c4 = lane & 7;               // float4 col group
                const int rbase = (wid - 2) * 128 + (lane >> 3) * 16;
                #pragma unroll
                for (int i = 0; i < 16; ++i) {
                    const int row = rbase + i;
                    const uint2 m = mask2[ph][row >> 5][row & 31];
                    float4 vv;
                    vv.x = (float)((m.x >> (2 * c4)) & 1u);      // ch 4c4+0
                    vv.y = (float)((m.y >> (2 * c4)) & 1u);      // ch 4c4+1
                    vv.z = (float)((m.x >> (2 * c4 + 1)) & 1u);  // ch 4c4+2
                    vv.w = (float)((m.y >> (2 * c4 + 1)) & 1u);  // ch 4c4+3
                    *(float4*)(sbase + (size_t)(tb + row) * LIF_D + 4 * c4) = vv;
                }
                asm volatile("s_waitcnt lgkmcnt(0)" ::: "memory");
            }
        }
        __builtin_amdgcn_s_barrier();
        asm volatile("" ::: "memory");
    }

    // ---- epilogue: flush masks of phase NH-1; store final membrane ----
    if (wid >= 2) {
        const int ph = (NH - 1) & 1;
        const int tb = (NH - 1) * CHUNK;
        const int c4 = lane & 7;
        const int rbase = (wid - 2) * 128 + (lane >> 3) * 16;
        #pragma unroll
        for (int i = 0; i < 16; ++i) {
            const int row = rbase + i;
            const uint2 m = mask2[ph][row >> 5][row & 31];
            float4 vv;
            vv.x = (float)((m.x >> (2 * c4)) & 1u);
            vv.y = (float)((m.y >> (2 * c4)) & 1u);
            vv.z = (float)((m.x >> (2 * c4 + 1)) & 1u);
            vv.w = (float)((m.y >> (2 * c4 + 1)) & 1u);
            *(float4*)(sbase + (size_t)(tb + row) * LIF_D + 4 * c4) = vv;
        }
    } else if (wid == 0 && lane < 16) {
        *(float2*)&mem_out[bb * LIF_D + ch0 + 2 * lane]
            = make_float2(memA, memB);
    }
}

extern "C" void kernel_launch(void* const* d_in, const int* in_sizes, int n_in,
                              void* d_out, int out_size, void* d_ws, size_t ws_size,
                              hipStream_t stream) {
    const float* current  = (const float*)d_in[0];   // [8, 4096, 1024]
    const float* membrane = (const float*)d_in[1];   // [8, 1024]

    float* spikes  = (float*)d_out;                                 // [8,4096,1024]
    float* mem_out = (float*)d_out + (size_t)LIF_B * LIF_S * LIF_D; // [8,1024]

    dim3 block(256);                   // w0 consumer, w1 producer, w2-3 writers
    dim3 grid(LIF_B * LIF_D / CPB);    // 256 blocks (32 channels each)

    hipLaunchKernelGGL(lif_v12_kernel, grid, block, 0, stream,
                       current, membrane, spikes, mem_out);
}